// Round 1
// baseline (15789.226 us; speedup 1.0000x reference)
//
#include <hip/hip_runtime.h>
#include <cstdint>
#include <cstddef>

#define VOCAB 32000
#define EMBED 512
#define HID   512
#define BATCH 64
#define TSTEPS 64

// ---------------------------------------------------------------------------
// Kernel A: one LSTM step.
//  grid = 256 blocks, block = 256 threads. Block handles j0 = 2*blockIdx.x,
//  i.e. 2 hidden columns x 4 gates = 8 gate rows, for all 64 batches.
//  Stages the 8 w_ih rows + 8 w_hh rows in LDS (32 KB), each thread
//  accumulates 2 (row, batch) dot products, then an in-block pointwise
//  epilogue applies the LSTM cell update (it has all 4 gates for its j's).
//  Also decodes prev tokens from the packed argmax slots and zeroes the
//  current step's slots (block 0).
// ---------------------------------------------------------------------------
__global__ __launch_bounds__(256) void lstm_step_kernel(
    const float* __restrict__ emb,
    const float* __restrict__ w_ih,
    const float* __restrict__ w_hh,
    const float* __restrict__ b_ih,
    const float* __restrict__ b_hh,
    const int*   __restrict__ start_tok,
    const unsigned long long* __restrict__ slot_prev,
    unsigned long long* __restrict__ slot_cur,
    const float* __restrict__ h_prev,
    const float* __restrict__ c_prev,
    float* __restrict__ h_out,
    float* __restrict__ c_out,
    float* __restrict__ h_t,        // [HID][BATCH] transposed h for logits GEMM
    int is_first)
{
    __shared__ float wih_s[8 * 512];
    __shared__ float whh_s[8 * 512];
    __shared__ float gate_s[8 * 64];

    const int tid = threadIdx.x;
    const int j0  = blockIdx.x * 2;

    // zero this step's argmax slots (kernel C of this step runs after us)
    if (blockIdx.x == 0 && tid < BATCH) slot_cur[tid] = 0ULL;

    // stage weights: local row r -> gate g=(r>>1), jj=(r&1); W row = g*512 + j0 + jj
    for (int idx = tid; idx < 8 * 512; idx += 256) {
        int r = idx >> 9, k = idx & 511;
        int row = ((r >> 1) * HID) + j0 + (r & 1);
        wih_s[idx] = w_ih[(size_t)row * EMBED + k];
        whh_s[idx] = w_hh[(size_t)row * HID + k];
    }
    __syncthreads();

    const int r  = tid >> 5;   // 0..7 local gate-row
    const int b0 = tid & 31;   // handles batches b0 and b0+32

    int tokA, tokB;
    if (is_first) {
        tokA = start_tok[0];
        tokB = tokA;
    } else {
        tokA = (int)(0xFFFFFFFFu - (unsigned)(slot_prev[b0]      & 0xFFFFFFFFull));
        tokB = (int)(0xFFFFFFFFu - (unsigned)(slot_prev[b0 + 32] & 0xFFFFFFFFull));
    }

    const float4* xA  = (const float4*)(emb + (size_t)tokA * EMBED);
    const float4* xB  = (const float4*)(emb + (size_t)tokB * EMBED);
    const float4* hA  = (const float4*)(h_prev + (size_t)b0 * HID);
    const float4* hB  = (const float4*)(h_prev + (size_t)(b0 + 32) * HID);
    const float4* wi4 = (const float4*)(wih_s + r * 512);
    const float4* wh4 = (const float4*)(whh_s + r * 512);

    float accA = 0.f, accB = 0.f;
#pragma unroll 2
    for (int k4 = 0; k4 < 128; ++k4) {
        float4 wi = wi4[k4], wh = wh4[k4];
        float4 a  = xA[k4],  bb = xB[k4];
        float4 ha = hA[k4],  hb = hB[k4];
        accA += wi.x * a.x + wi.y * a.y + wi.z * a.z + wi.w * a.w
              + wh.x * ha.x + wh.y * ha.y + wh.z * ha.z + wh.w * ha.w;
        accB += wi.x * bb.x + wi.y * bb.y + wi.z * bb.z + wi.w * bb.w
              + wh.x * hb.x + wh.y * hb.y + wh.z * hb.z + wh.w * hb.w;
    }
    gate_s[r * 64 + b0]      = accA;
    gate_s[r * 64 + b0 + 32] = accB;
    __syncthreads();

    if (tid < 128) {
        int jj = tid >> 6;   // 0/1
        int b  = tid & 63;
        int j  = j0 + jj;
        float iv = gate_s[(0 * 2 + jj) * 64 + b] + b_ih[0 * HID + j] + b_hh[0 * HID + j];
        float fv = gate_s[(1 * 2 + jj) * 64 + b] + b_ih[1 * HID + j] + b_hh[1 * HID + j];
        float gv = gate_s[(2 * 2 + jj) * 64 + b] + b_ih[2 * HID + j] + b_hh[2 * HID + j];
        float ov = gate_s[(3 * 2 + jj) * 64 + b] + b_ih[3 * HID + j] + b_hh[3 * HID + j];
        float ig = 1.f / (1.f + expf(-iv));
        float fg = 1.f / (1.f + expf(-fv));
        float gg = tanhf(gv);
        float og = 1.f / (1.f + expf(-ov));
        float cn = fg * c_prev[(size_t)b * HID + j] + ig * gg;
        float hn = og * tanhf(cn);
        c_out[(size_t)b * HID + j] = cn;
        h_out[(size_t)b * HID + j] = hn;
        h_t[(size_t)j * BATCH + b] = hn;   // transposed, coalesced
    }
}

// ---------------------------------------------------------------------------
// Kernel B: logits = h @ fc_w^T + fc_b, fused argmax (packed u64 atomicMax)
//  and transposed store into out[b][t][v].
//  grid = 1000 blocks x 64 threads. lane = batch, block covers 32 vocab rows.
//  fc_w loads are wave-uniform float4 (1 transaction); h_t loads coalesced.
// ---------------------------------------------------------------------------
__global__ __launch_bounds__(64) void logits_kernel(
    const float* __restrict__ h_t,   // [HID][BATCH]
    const float* __restrict__ fc_w,  // [VOCAB][HID]
    const float* __restrict__ fc_b,  // [VOCAB]
    float* __restrict__ out,         // [BATCH][TSTEPS][VOCAB]
    unsigned long long* __restrict__ slot,  // [BATCH] for this step
    int t)
{
    __shared__ float tr[32 * 65];
    const int lane = threadIdx.x;          // = batch
    const int v0   = blockIdx.x * 32;

    float acc[32];
#pragma unroll
    for (int i = 0; i < 32; ++i) acc[i] = 0.f;

    const float4* w4 = (const float4*)fc_w;  // row v starts at index v*128

#pragma unroll 1
    for (int k4 = 0; k4 < 128; ++k4) {
        int k = k4 * 4;
        float h0 = h_t[(k + 0) * BATCH + lane];
        float h1 = h_t[(k + 1) * BATCH + lane];
        float h2 = h_t[(k + 2) * BATCH + lane];
        float h3 = h_t[(k + 3) * BATCH + lane];
#pragma unroll
        for (int v = 0; v < 32; ++v) {
            float4 w = w4[(size_t)(v0 + v) * 128 + k4];
            acc[v] += w.x * h0 + w.y * h1 + w.z * h2 + w.w * h3;
        }
    }

    // bias (broadcast via shuffle)
    float fcb = (lane < 32) ? fc_b[v0 + lane] : 0.f;
#pragma unroll
    for (int v = 0; v < 32; ++v) acc[v] += __shfl(fcb, v);

    // local argmax (ascending v, strict > keeps first max like numpy)
    float bestv = acc[0];
    int   besti = 0;
#pragma unroll
    for (int v = 1; v < 32; ++v)
        if (acc[v] > bestv) { bestv = acc[v]; besti = v; }

    unsigned ub = __float_as_uint(bestv);
    ub = (ub & 0x80000000u) ? ~ub : (ub | 0x80000000u);  // order-preserving map
    unsigned long long packed =
        ((unsigned long long)ub << 32) |
        (unsigned long long)(0xFFFFFFFFu - (unsigned)(v0 + besti));
    atomicMax(&slot[lane], packed);

    // transpose through LDS (padded) and store coalesced in v
#pragma unroll
    for (int v = 0; v < 32; ++v) tr[v * 65 + lane] = acc[v];
    __syncthreads();

    const int vv   = lane & 31;
    const int boff = lane >> 5;  // 0/1
    for (int rr = 0; rr < 64; rr += 2) {
        int b = rr + boff;
        out[((size_t)b * TSTEPS + t) * VOCAB + v0 + vv] = tr[vv * 65 + b];
    }
}

// ---------------------------------------------------------------------------
// host launcher: 64 steps x (lstm_step, logits) stream-ordered
// ---------------------------------------------------------------------------
extern "C" void kernel_launch(void* const* d_in, const int* in_sizes, int n_in,
                              void* d_out, int out_size, void* d_ws, size_t ws_size,
                              hipStream_t stream)
{
    const float* hidden    = (const float*)d_in[0];
    const float* cell      = (const float*)d_in[1];
    const int*   start_tok = (const int*)d_in[3];
    const float* emb       = (const float*)d_in[4];
    const float* w_ih      = (const float*)d_in[5];
    const float* w_hh      = (const float*)d_in[6];
    const float* b_ih      = (const float*)d_in[7];
    const float* b_hh      = (const float*)d_in[8];
    const float* fc_w      = (const float*)d_in[9];
    const float* fc_b      = (const float*)d_in[10];
    float* out = (float*)d_out;

    char* ws = (char*)d_ws;
    unsigned long long* slots = (unsigned long long*)ws;          // [T][B]
    float* h_rm = (float*)(ws + (size_t)TSTEPS * BATCH * 8);      // [2][B][H]
    float* c_rm = h_rm + 2 * BATCH * HID;                         // [2][B][H]
    float* h_t  = c_rm + 2 * BATCH * HID;                         // [H][B]

    for (int t = 0; t < TSTEPS; ++t) {
        const float* hp = (t == 0) ? hidden : h_rm + (size_t)((t - 1) & 1) * BATCH * HID;
        const float* cp = (t == 0) ? cell   : c_rm + (size_t)((t - 1) & 1) * BATCH * HID;
        float* ho = h_rm + (size_t)(t & 1) * BATCH * HID;
        float* co = c_rm + (size_t)(t & 1) * BATCH * HID;
        const unsigned long long* sp = (t == 0) ? slots : slots + (size_t)(t - 1) * BATCH;
        unsigned long long* sc = slots + (size_t)t * BATCH;

        hipLaunchKernelGGL(lstm_step_kernel, dim3(256), dim3(256), 0, stream,
                           emb, w_ih, w_hh, b_ih, b_hh, start_tok,
                           sp, sc, hp, cp, ho, co, h_t, (t == 0) ? 1 : 0);

        hipLaunchKernelGGL(logits_kernel, dim3(1000), dim3(64), 0, stream,
                           h_t, fc_w, fc_b, out, sc, t);
    }
}